// Round 3
// baseline (817.174 us; speedup 1.0000x reference)
//
#include <hip/hip_runtime.h>
#include <hip/hip_bf16.h>

typedef __attribute__((ext_vector_type(8))) short bf16x8;
typedef __attribute__((ext_vector_type(4))) float f32x4;

#define B_ 2
#define S_ 2048
#define E_ 1024
#define H_ 16
#define DH_ 64

// ---------------- cast features fp32 -> bf16 ----------------
__global__ __launch_bounds__(256) void cast_bf16_kernel(const float* __restrict__ x,
                                                        __hip_bfloat16* __restrict__ y) {
  int i = blockIdx.x * 256 + threadIdx.x;  // one float4 per thread, grid sized exactly
  float4 v = reinterpret_cast<const float4*>(x)[i];
  __hip_bfloat16 t[4] = {__float2bfloat16(v.x), __float2bfloat16(v.y),
                         __float2bfloat16(v.z), __float2bfloat16(v.w)};
  reinterpret_cast<uint2*>(y)[i] = *reinterpret_cast<uint2*>(t);
}

// ---------------- transpose + cast weight: Wt[n][k] = W[k][n] ----------------
__global__ __launch_bounds__(256) void transpose_cast_kernel(const float* __restrict__ W,
                                                             __hip_bfloat16* __restrict__ Wt) {
  __shared__ float t[32][33];
  int bx = blockIdx.x * 32, by = blockIdx.y * 32;
  int tx = threadIdx.x & 31, ty = threadIdx.x >> 5;  // ty 0..7
  for (int r = 0; r < 32; r += 8)
    t[ty + r][tx] = W[(size_t)(by + ty + r) * E_ + bx + tx];
  __syncthreads();
  for (int r = 0; r < 32; r += 8)
    Wt[(size_t)(bx + ty + r) * E_ + by + tx] = __float2bfloat16(t[tx][ty + r]);
}

// ---------------- generic GEMM: C[m][n] = sum_k A[m][k] * Bt[n][k] (+bias) ----------------
#define GT 64
#define GBK 32
__global__ __launch_bounds__(256) void gemm_bt_kernel(
    const __hip_bfloat16* __restrict__ A,   // [M][K]
    const __hip_bfloat16* __restrict__ Bt,  // [N][K]
    const float* __restrict__ bias_m,       // may be null
    const float* __restrict__ bias_n,       // may be null
    __hip_bfloat16* __restrict__ Cb,        // bf16 out (if Cf null)
    float* __restrict__ Cf,                 // fp32 out (takes precedence)
    int M, int N, int K) {
  __shared__ __hip_bfloat16 As[GT][GBK + 8];
  __shared__ __hip_bfloat16 Bs[GT][GBK + 8];
  const int tid = threadIdx.x;
  const int lane = tid & 63;
  const int wave = tid >> 6;
  const int l15 = lane & 15, l4 = lane >> 4;
  const int m0 = blockIdx.y * GT;
  const int n0 = blockIdx.x * GT;
  const int wm = (wave & 1) * 32;
  const int wn = (wave >> 1) * 32;
  const int srow = tid >> 2;           // 0..63
  const int schunk = (tid & 3) * 8;    // k offset in tile
  f32x4 acc[2][2] = {};
  for (int k0 = 0; k0 < K; k0 += GBK) {
    __syncthreads();
    *reinterpret_cast<bf16x8*>(&As[srow][schunk]) =
        *reinterpret_cast<const bf16x8*>(&A[(size_t)(m0 + srow) * K + k0 + schunk]);
    *reinterpret_cast<bf16x8*>(&Bs[srow][schunk]) =
        *reinterpret_cast<const bf16x8*>(&Bt[(size_t)(n0 + srow) * K + k0 + schunk]);
    __syncthreads();
    bf16x8 af[2], bfr[2];
#pragma unroll
    for (int i = 0; i < 2; ++i)
      af[i] = *reinterpret_cast<const bf16x8*>(&As[wm + i * 16 + l15][l4 * 8]);
#pragma unroll
    for (int j = 0; j < 2; ++j)
      bfr[j] = *reinterpret_cast<const bf16x8*>(&Bs[wn + j * 16 + l15][l4 * 8]);
#pragma unroll
    for (int i = 0; i < 2; ++i)
#pragma unroll
      for (int j = 0; j < 2; ++j)
        acc[i][j] = __builtin_amdgcn_mfma_f32_16x16x32_bf16(af[i], bfr[j], acc[i][j], 0, 0, 0);
  }
#pragma unroll
  for (int i = 0; i < 2; ++i)
#pragma unroll
    for (int j = 0; j < 2; ++j)
#pragma unroll
      for (int r = 0; r < 4; ++r) {
        int row = m0 + wm + i * 16 + l4 * 4 + r;
        int col = n0 + wn + j * 16 + l15;
        float v = acc[i][j][r];
        if (bias_m) v += bias_m[row];
        if (bias_n) v += bias_n[col];
        if (Cf) Cf[(size_t)row * N + col] = v;
        else    Cb[(size_t)row * N + col] = __float2bfloat16(v);
      }
}

// ---------------- fused attention: two-pass exact softmax, writes attn + ctx ----------------
#define QBLK 64
#define KBLK 128
__global__ __launch_bounds__(256) void attn_kernel(
    const __hip_bfloat16* __restrict__ Qb,   // [B*S][E]
    const __hip_bfloat16* __restrict__ Kb,   // [B*S][E]
    const __hip_bfloat16* __restrict__ Vtb,  // [E][B*S]
    const float* __restrict__ mask,          // [B][S]
    float* __restrict__ attn_out,            // [B*H][S][S]
    __hip_bfloat16* __restrict__ Ctxb) {     // [B*S][E]
  __shared__ __hip_bfloat16 Qs[QBLK][DH_ + 8];
  __shared__ __hip_bfloat16 Ks[KBLK][DH_ + 8];
  __shared__ __hip_bfloat16 Vs[DH_][KBLK + 8];
  __shared__ __hip_bfloat16 Ps[QBLK][KBLK + 8];
  const int tid = threadIdx.x;
  const int lane = tid & 63;
  const int wave = tid >> 6;           // wave owns q rows [wave*16, wave*16+16)
  const int l15 = lane & 15, l4 = lane >> 4;
  const int bh = blockIdx.y;
  const int b = bh >> 4;               // / H_
  const int h = bh & 15;               // % H_
  const int q0 = blockIdx.x * QBLK;

  {  // stage Q once
    int row = tid >> 3, c = (tid & 7) * 8;
#pragma unroll
    for (int p = 0; p < 2; ++p) {
      int r = row + p * 32;
      *reinterpret_cast<bf16x8*>(&Qs[r][c]) =
          *reinterpret_cast<const bf16x8*>(&Qb[(size_t)(b * S_ + q0 + r) * E_ + h * DH_ + c]);
    }
  }
  __syncthreads();
  bf16x8 qa0 = *reinterpret_cast<const bf16x8*>(&Qs[wave * 16 + l15][l4 * 8]);
  bf16x8 qa1 = *reinterpret_cast<const bf16x8*>(&Qs[wave * 16 + l15][32 + l4 * 8]);

  float mrow[4], srow[4];
#pragma unroll
  for (int r = 0; r < 4; ++r) { mrow[r] = -1e30f; srow[r] = 0.f; }

  // ---- pass A: row max + exp-sum ----
  for (int kt = 0; kt < S_ / KBLK; ++kt) {
    __syncthreads();
    { int row = tid >> 3, c = (tid & 7) * 8;
#pragma unroll
      for (int p = 0; p < 4; ++p) {
        int r = row + p * 32;
        *reinterpret_cast<bf16x8*>(&Ks[r][c]) =
            *reinterpret_cast<const bf16x8*>(&Kb[(size_t)(b * S_ + kt * KBLK + r) * E_ + h * DH_ + c]);
      }
    }
    __syncthreads();
    f32x4 sv[8];
#pragma unroll
    for (int j = 0; j < 8; ++j) {
      bf16x8 kb0 = *reinterpret_cast<const bf16x8*>(&Ks[j * 16 + l15][l4 * 8]);
      bf16x8 kb1 = *reinterpret_cast<const bf16x8*>(&Ks[j * 16 + l15][32 + l4 * 8]);
      f32x4 a = {};
      a = __builtin_amdgcn_mfma_f32_16x16x32_bf16(qa0, kb0, a, 0, 0, 0);
      a = __builtin_amdgcn_mfma_f32_16x16x32_bf16(qa1, kb1, a, 0, 0, 0);
      float mv = mask[b * S_ + kt * KBLK + j * 16 + l15] * -1e9f;
#pragma unroll
      for (int r = 0; r < 4; ++r) sv[j][r] = a[r] * 0.125f + mv;
    }
#pragma unroll
    for (int r = 0; r < 4; ++r) {
      float tmax = sv[0][r];
#pragma unroll
      for (int j = 1; j < 8; ++j) tmax = fmaxf(tmax, sv[j][r]);
      for (int m = 1; m < 16; m <<= 1) tmax = fmaxf(tmax, __shfl_xor(tmax, m, 64));
      float newm = fmaxf(mrow[r], tmax);
      float ls = 0.f;
#pragma unroll
      for (int j = 0; j < 8; ++j) ls += __expf(sv[j][r] - newm);
      for (int m = 1; m < 16; m <<= 1) ls += __shfl_xor(ls, m, 64);
      srow[r] = srow[r] * __expf(mrow[r] - newm) + ls;
      mrow[r] = newm;
    }
  }
  float inv_s[4];
#pragma unroll
  for (int r = 0; r < 4; ++r) inv_s[r] = 1.0f / srow[r];

  // ---- pass B: recompute logits -> attn out + PV ----
  f32x4 ctx[4] = {};
  float* attn_base = attn_out + (size_t)bh * S_ * S_;
  for (int kt = 0; kt < S_ / KBLK; ++kt) {
    __syncthreads();
    { int row = tid >> 3, c = (tid & 7) * 8;
#pragma unroll
      for (int p = 0; p < 4; ++p) {
        int r = row + p * 32;
        *reinterpret_cast<bf16x8*>(&Ks[r][c]) =
            *reinterpret_cast<const bf16x8*>(&Kb[(size_t)(b * S_ + kt * KBLK + r) * E_ + h * DH_ + c]);
      }
    }
    { int d = tid >> 4, c = (tid & 15) * 8;
#pragma unroll
      for (int p = 0; p < 4; ++p) {
        int dd = d + p * 16;
        *reinterpret_cast<bf16x8*>(&Vs[dd][c]) =
            *reinterpret_cast<const bf16x8*>(&Vtb[(size_t)(h * DH_ + dd) * (B_ * S_) + b * S_ + kt * KBLK + c]);
      }
    }
    __syncthreads();
#pragma unroll
    for (int j = 0; j < 8; ++j) {
      bf16x8 kb0 = *reinterpret_cast<const bf16x8*>(&Ks[j * 16 + l15][l4 * 8]);
      bf16x8 kb1 = *reinterpret_cast<const bf16x8*>(&Ks[j * 16 + l15][32 + l4 * 8]);
      f32x4 a = {};
      a = __builtin_amdgcn_mfma_f32_16x16x32_bf16(qa0, kb0, a, 0, 0, 0);
      a = __builtin_amdgcn_mfma_f32_16x16x32_bf16(qa1, kb1, a, 0, 0, 0);
      float mv = mask[b * S_ + kt * KBLK + j * 16 + l15] * -1e9f;
#pragma unroll
      for (int r = 0; r < 4; ++r) {
        float p = __expf(a[r] * 0.125f + mv - mrow[r]) * inv_s[r];
        int row = wave * 16 + l4 * 4 + r;
        int col = j * 16 + l15;
        attn_base[(size_t)(q0 + row) * S_ + kt * KBLK + col] = p;
        Ps[row][col] = __float2bfloat16(p);
      }
    }
    __syncthreads();
#pragma unroll
    for (int kk = 0; kk < 4; ++kk) {
      bf16x8 pa = *reinterpret_cast<const bf16x8*>(&Ps[wave * 16 + l15][kk * 32 + l4 * 8]);
#pragma unroll
      for (int j2 = 0; j2 < 4; ++j2) {
        bf16x8 vb = *reinterpret_cast<const bf16x8*>(&Vs[j2 * 16 + l15][kk * 32 + l4 * 8]);
        ctx[j2] = __builtin_amdgcn_mfma_f32_16x16x32_bf16(pa, vb, ctx[j2], 0, 0, 0);
      }
    }
  }
#pragma unroll
  for (int j2 = 0; j2 < 4; ++j2)
#pragma unroll
    for (int r = 0; r < 4; ++r) {
      int row = wave * 16 + l4 * 4 + r;
      int col = j2 * 16 + l15;
      Ctxb[(size_t)(b * S_ + q0 + row) * E_ + h * DH_ + col] = __float2bfloat16(ctx[j2][r]);
    }
}

extern "C" void kernel_launch(void* const* d_in, const int* in_sizes, int n_in,
                              void* d_out, int out_size, void* d_ws, size_t ws_size,
                              hipStream_t stream) {
  const float* features = (const float*)d_in[0];
  const float* mask     = (const float*)d_in[1];
  const float* Wq       = (const float*)d_in[2];
  const float* bq       = (const float*)d_in[3];
  const float* Wk       = (const float*)d_in[4];
  const float* bk       = (const float*)d_in[5];
  const float* Wv       = (const float*)d_in[6];
  const float* bv       = (const float*)d_in[7];
  const float* Wo       = (const float*)d_in[8];
  const float* bo       = (const float*)d_in[9];
  float* out  = (float*)d_out;
  float* attn = out + (size_t)B_ * S_ * E_;

  char* ws = (char*)d_ws;
  __hip_bfloat16* Xbf  = (__hip_bfloat16*)(ws);                  // 8 MB  [4096][1024]
  __hip_bfloat16* WqT  = (__hip_bfloat16*)(ws + (8ull  << 20));  // 2 MB  [1024][1024]
  __hip_bfloat16* WkT  = (__hip_bfloat16*)(ws + (10ull << 20));
  __hip_bfloat16* WvT  = (__hip_bfloat16*)(ws + (12ull << 20));
  __hip_bfloat16* WoT  = (__hip_bfloat16*)(ws + (14ull << 20));
  __hip_bfloat16* Qb   = (__hip_bfloat16*)(ws + (16ull << 20));  // 8 MB [4096][1024]
  __hip_bfloat16* Kb   = (__hip_bfloat16*)(ws + (24ull << 20));
  __hip_bfloat16* Vtb  = (__hip_bfloat16*)(ws + (32ull << 20));  // 8 MB [1024][4096]
  __hip_bfloat16* Ctxb = (__hip_bfloat16*)(ws + (40ull << 20));  // 8 MB [4096][1024]

  cast_bf16_kernel<<<(B_ * S_ * E_ / 4) / 256, 256, 0, stream>>>(features, Xbf);
  dim3 tg(E_ / 32, E_ / 32);
  transpose_cast_kernel<<<tg, 256, 0, stream>>>(Wq, WqT);
  transpose_cast_kernel<<<tg, 256, 0, stream>>>(Wk, WkT);
  transpose_cast_kernel<<<tg, 256, 0, stream>>>(Wv, WvT);
  transpose_cast_kernel<<<tg, 256, 0, stream>>>(Wo, WoT);

  // Q = X Wq + bq  -> [token][e]
  gemm_bt_kernel<<<dim3(E_ / GT, B_ * S_ / GT), 256, 0, stream>>>(
      Xbf, WqT, nullptr, bq, Qb, nullptr, B_ * S_, E_, E_);
  // K = X Wk + bk  -> [token][e]
  gemm_bt_kernel<<<dim3(E_ / GT, B_ * S_ / GT), 256, 0, stream>>>(
      Xbf, WkT, nullptr, bk, Kb, nullptr, B_ * S_, E_, E_);
  // Vt = (X Wv + bv)^T -> [e][token]   (C[e][tok] = sum_k WvT[e][k] * X[tok][k], bias per-row)
  gemm_bt_kernel<<<dim3(B_ * S_ / GT, E_ / GT), 256, 0, stream>>>(
      WvT, Xbf, bv, nullptr, Vtb, nullptr, E_, B_ * S_, E_);

  attn_kernel<<<dim3(S_ / QBLK, B_ * H_), 256, 0, stream>>>(Qb, Kb, Vtb, mask, attn, Ctxb);

  // out = Ctx Wo + bo -> fp32 to d_out
  gemm_bt_kernel<<<dim3(E_ / GT, B_ * S_ / GT), 256, 0, stream>>>(
      Ctxb, WoT, nullptr, bo, nullptr, out, B_ * S_, E_, E_);
}